// Round 11
// baseline (203.621 us; speedup 1.0000x reference)
//
#include <hip/hip_runtime.h>

// ============================================================================
// Algebraic collapse (layers 2..11 + head linear; A commutes with W):
//   out = A^10 x1 w~ + sum_l gamma_l A^(9-l) 1 + b_out
// Round-11: the unmeasured cell of the round ledger --
//   tagged-dataflow chain (33 blocks, R8/R9-proven, no barriers, enough CUs
//   for the 10MB weight stream)  +  one-shot FLAG rendezvous (R4/R10-proven;
//   graph polls 33 flags, NOT 512 value-tags -- R9's hypothesized +23us).
// Single-variable A/B: vs R9 isolates the rendezvous mechanism; vs R4
// isolates the chain mechanism.
//   * graph front-end: R4/R9 verbatim (3 group barriers, plain 4B sc1 esrc).
//   * chain: 33 x 1024, 1 row/wave, tagged vslab steps 1..9; FINAL outputs
//     (w~ -> wbuf, gammas -> gamma_f) are plain sc1 floats ordered by rdv.
//   * proj + 10 Horner steps: R4/R9-identical sc1 ping-pong + group_bar.
// ============================================================================

#define N_NODES 10000
#define N_EDGES 160000
#define DEPTH   10

#define NB_G 40                  // graph blocks
#define NB_C 33                  // chain blocks (33*16 waves = 528 >= 513)
#define NB   (NB_G + NB_C)       // 73 blocks x 1024: all co-resident
#define BT   1024
#define NTHG (NB_G * BT)         // 40960 graph threads
#define NPB  250                 // nodes per graph block (40*250 = 10000)
#define ECAP 8192                // LDS edge-slice cap (expected ~4000)

typedef unsigned long long u64;

// ---- agent-scope (L3-coherent) accessors -----------------------------------
__device__ __forceinline__ int ldAi(const int* p) {
    return __hip_atomic_load(p, __ATOMIC_RELAXED, __HIP_MEMORY_SCOPE_AGENT);
}
__device__ __forceinline__ void stAi(int* p, int v) {
    __hip_atomic_store(p, v, __ATOMIC_RELAXED, __HIP_MEMORY_SCOPE_AGENT);
}
__device__ __forceinline__ float ldAf(const float* p) {
    return __hip_atomic_load(p, __ATOMIC_RELAXED, __HIP_MEMORY_SCOPE_AGENT);
}
__device__ __forceinline__ void stAf(float* p, float v) {
    __hip_atomic_store(p, v, __ATOMIC_RELAXED, __HIP_MEMORY_SCOPE_AGENT);
}
__device__ __forceinline__ u64 ld8(const u64* p) {
    return __hip_atomic_load(p, __ATOMIC_RELAXED, __HIP_MEMORY_SCOPE_AGENT);
}
__device__ __forceinline__ void st8(u64* p, u64 v) {
    __hip_atomic_store(p, v, __ATOMIC_RELAXED, __HIP_MEMORY_SCOPE_AGENT);
}
__device__ __forceinline__ u64 packf(float f) {
    union { float f; unsigned u; } c; c.f = f;
    return (1ull << 32) | (u64)c.u;
}
__device__ __forceinline__ float unpackf(u64 v) {
    union { unsigned u; float f; } c; c.u = (unsigned)v;
    return c.f;
}
#define READY(v) ((unsigned)((v) >> 32) != 0u)

// ---- R4-proven group barrier: stride-32 flags, one poll thread per flag ----
__device__ __forceinline__ void group_bar(int* flags, int gi, int n, int target) {
    const int tx = threadIdx.x;
    asm volatile("s_waitcnt vmcnt(0)" ::: "memory");  // this wave's sc1 at L3
    __syncthreads();                                  // all waves drained
    if (tx == 0) stAi(&flags[gi * 32], target);
    if (tx < n && tx != gi) {
        while (ldAi(&flags[tx * 32]) < target) __builtin_amdgcn_s_sleep(1);
    }
    __syncthreads();
}

extern "C" __global__ void __launch_bounds__(BT, 1) gcn_mega(
    const float* __restrict__ features, const float* __restrict__ W_in,
    const float* __restrict__ b_in, const float* __restrict__ Ws,
    const float* __restrict__ bs, const float* __restrict__ W_out,
    const float* __restrict__ b_out, const int* __restrict__ src,
    const int* __restrict__ dst, float* __restrict__ out,
    int* g_arrive, int* rdv, u64* vslab, float* wbuf, float* gamma_f,
    int* deg, int* esrc, float* rb0, float* rb1, int* row_ptr, int* cursor)
{
    __shared__ int   lds_e[ECAP];     // 32 KB  edge slice (src ids)
    __shared__ float s_Wb[4096];      // 16 KB  [512][8]: {W_in col (6), b, pad}
    __shared__ float s_vt[512];       //  2 KB  vtilde
    __shared__ float s_gam[16];
    __shared__ int   s_info[2];
    __shared__ int   s_wsum[16];

    const int tx = threadIdx.x;
    const int bx = blockIdx.x;

    // ======================= CHAIN GROUP (blocks >= NB_G) ===================
    // R8/R9-proven tagged dataflow (steps 1..9); final outputs plain + rdv.
    if (bx >= NB_G) {
        const int gi   = bx - NB_G;
        const int cw   = gi * 16 + (tx >> 6);         // 0..527
        const int lane = tx & 63;
        if (cw <= 512) {
            for (int s = 0; s < DEPTH; s++) {
                const int l = 9 - s;
                const float* rowp = (cw < 512)
                    ? (Ws + (size_t)l * (512 * 512) + (size_t)cw * 512)
                    : (bs + (size_t)l * 512);
                float wrow[8];
#pragma unroll
                for (int c = 0; c < 8; c++) wrow[c] = rowp[lane + 64 * c];
                float vin[8];
                if (s == 0) {
#pragma unroll
                    for (int c = 0; c < 8; c++) vin[c] = W_out[lane + 64 * c];
                } else {
                    const u64* vb = vslab + (size_t)s * 512;
                    u64 raw[8];
#pragma unroll
                    for (int c = 0; c < 8; c++) raw[c] = ld8(vb + lane + 64 * c);
                    for (;;) {
                        bool ok = true;
#pragma unroll
                        for (int c = 0; c < 8; c++)
                            if (!READY(raw[c])) { ok = false; raw[c] = ld8(vb + lane + 64 * c); }
                        if (ok) break;
                        __builtin_amdgcn_s_sleep(1);
                    }
#pragma unroll
                    for (int c = 0; c < 8; c++) vin[c] = unpackf(raw[c]);
                }
                float acc = 0.f;
#pragma unroll
                for (int c = 0; c < 8; c++) acc += wrow[c] * vin[c];
#pragma unroll
                for (int off = 32; off; off >>= 1) acc += __shfl_xor(acc, off, 64);
                if (lane == 0) {
                    if (cw < 512) {
                        if (s < DEPTH - 1) st8(vslab + (size_t)(s + 1) * 512 + cw, packf(acc));
                        else               stAf(&wbuf[cw], acc);   // ordered by rdv
                    } else {
                        stAf(&gamma_f[l], acc);                    // ordered by rdv
                    }
                }
            }
        }
        // one-shot publish (R4/R10-proven): drain, sync, flag
        asm volatile("s_waitcnt vmcnt(0)" ::: "memory");
        __syncthreads();
        if (tx == 0) stAi(&rdv[gi * 32], 1);
        return;
    }

    // ======================= GRAPH GROUP (blocks < NB_G) ====================
    const int gi = bx;
    int gt = 1;

    // -------- P0: degree count + per-block W_in pack ------------------------
    {
        const int t0 = bx * BT + tx;
        for (int e = t0; e < N_EDGES; e += NTHG) atomicAdd(&deg[dst[e]], 1);
    }
    for (int idx = tx; idx < 4096; idx += BT) {
        int j = idx >> 3, k = idx & 7;
        float v = 0.f;
        if (k < 6) v = W_in[k * 512 + j];          // read-only cached loads
        else if (k == 6) v = b_in[j];
        s_Wb[idx] = v;
    }
    group_bar(g_arrive, gi, NB_G, gt++);

    // -------- P1: prefix scan (graph block 0, shuffle-based) ----------------
    if (bx == 0) {
        const int lane = tx & 63, wid = tx >> 6;    // 16 waves
        const bool sact = tx < 1000;                // 1000 x 10 = 10000
        int lv[10];
        int ssum = 0;
        if (sact) {
#pragma unroll
            for (int i = 0; i < 10; i++) { lv[i] = ldAi(&deg[tx * 10 + i]); ssum += lv[i]; }
        }
        int v = ssum;                               // wave inclusive scan
#pragma unroll
        for (int off = 1; off < 64; off <<= 1) {
            int u = __shfl_up(v, off, 64);
            if (lane >= off) v += u;
        }
        if (lane == 63) s_wsum[wid] = v;
        __syncthreads();
        if (wid == 0) {                             // scan the 16 wave totals
            int w = (lane < 16) ? s_wsum[lane] : 0;
#pragma unroll
            for (int off = 1; off < 16; off <<= 1) {
                int u = __shfl_up(w, off, 64);
                if (lane >= off) w += u;
            }
            if (lane < 16) s_wsum[lane] = w;
        }
        __syncthreads();
        if (sact) {
            int run = (wid ? s_wsum[wid - 1] : 0) + (v - ssum);  // exclusive
#pragma unroll
            for (int i = 0; i < 10; i++) {
                stAi(&row_ptr[tx * 10 + i], run);
                stAi(&cursor[tx * 10 + i], run);
                run += lv[i];
            }
            if (tx == 999) stAi(&row_ptr[N_NODES], run);
        }
    }
    group_bar(g_arrive, gi, NB_G, gt++);

    // -------- P2: CSR fill (plain 4-byte sc1 entries; R4-proven) ------------
    {
        const int t0 = bx * BT + tx;
        for (int e = t0; e < N_EDGES; e += NTHG) {
            int d = dst[e];
            int sv = src[e];
            int pos = atomicAdd(&cursor[d], 1);
            stAi(&esrc[pos], sv);
        }
    }
    group_bar(g_arrive, gi, NB_G, gt++);

    // -------- P3: stage edge slice -> LDS; aggregate features ---------------
    if (tx == 0) {
        s_info[0] = ldAi(&row_ptr[bx * NPB]);
        s_info[1] = ldAi(&row_ptr[bx * NPB + NPB]);
    }
    __syncthreads();
    const int e_lo = s_info[0];
    const int slen = s_info[1] - e_lo;
    const bool use_lds = (slen <= ECAP);
    if (use_lds) {
        for (int i = tx; i < slen; i += BT) lds_e[i] = ldAi(&esrc[e_lo + i]);
    }
    __syncthreads();

    const int node = bx * NPB + (tx >> 2);          // 4 threads/node
    const int sub  = tx & 3;
    const bool act = tx < 4 * NPB;                  // 1000 active threads
    int ns = 0, ne = 0;
    float a0 = 0.f, a1 = 0.f, a2 = 0.f, a3 = 0.f, a4 = 0.f, a5 = 0.f;
    if (act) {
        ns = ldAi(&row_ptr[node]);
        ne = ldAi(&row_ptr[node + 1]);
        for (int pp = ns + sub; pp < ne; pp += 4) {
            int j;
            if (use_lds) j = lds_e[pp - e_lo];
            else         j = ldAi(&esrc[pp]);
            const float2* f = (const float2*)(features + (size_t)j * 6);
            float2 f0 = f[0], f1 = f[1], f2 = f[2];
            a0 += f0.x; a1 += f0.y; a2 += f1.x;
            a3 += f1.y; a4 += f2.x; a5 += f2.y;
        }
        a0 += __shfl_xor(a0, 1, 64); a0 += __shfl_xor(a0, 2, 64);
        a1 += __shfl_xor(a1, 1, 64); a1 += __shfl_xor(a1, 2, 64);
        a2 += __shfl_xor(a2, 1, 64); a2 += __shfl_xor(a2, 2, 64);
        a3 += __shfl_xor(a3, 1, 64); a3 += __shfl_xor(a3, 2, 64);
        a4 += __shfl_xor(a4, 1, 64); a4 += __shfl_xor(a4, 2, 64);
        a5 += __shfl_xor(a5, 1, 64); a5 += __shfl_xor(a5, 2, 64);
    }

    // -------- rendezvous: poll 33 one-shot rdv flags, then plain sc1 reads --
    if (tx < NB_C) {
        while (ldAi(&rdv[tx * 32]) < 1) __builtin_amdgcn_s_sleep(1);
    }
    __syncthreads();
    if (tx < 512) s_vt[tx] = ldAf(&wbuf[tx]);
    else if (tx < 512 + DEPTH) s_gam[tx - 512] = ldAf(&gamma_f[tx - 512]);
    __syncthreads();

    // -------- proj: r0 = relu(a . W_in + b_in) . w~ -> rb0 ------------------
    if (act) {
        const float4* Wb4 = (const float4*)s_Wb;
        float zacc = 0.f;
#pragma unroll 4
        for (int jj = 0; jj < 128; jj++) {
            int j = (jj << 2) | sub;                // 4-way split of j-range
            float4 wA = Wb4[2 * j];                 // w0..w3
            float4 wB = Wb4[2 * j + 1];             // w4, w5, b, pad
            float tv = wB.z + a0 * wA.x + a1 * wA.y + a2 * wA.z +
                       a3 * wA.w + a4 * wB.x + a5 * wB.y;
            zacc += fmaxf(tv, 0.f) * s_vt[j];
        }
        zacc += __shfl_xor(zacc, 1, 64);
        zacc += __shfl_xor(zacc, 2, 64);
        if (sub == 0) stAf(&rb0[node], zacc);
    }
    group_bar(g_arrive, gi, NB_G, gt++);

    // -------- Horner: r_{l+1} = A r_l + gamma[l]; sc1 ping-pong (proven) ----
    for (int l = 0; l < DEPTH; l++) {
        if (act) {
            const float* rin = (l & 1) ? rb1 : rb0;
            float h0 = 0.f, h1 = 0.f, h2 = 0.f, h3 = 0.f;
            int pp = ns + sub;
            if (use_lds) {
                for (; pp + 12 < ne; pp += 16) {
                    h0 += ldAf(&rin[lds_e[pp - e_lo]]);
                    h1 += ldAf(&rin[lds_e[pp + 4 - e_lo]]);
                    h2 += ldAf(&rin[lds_e[pp + 8 - e_lo]]);
                    h3 += ldAf(&rin[lds_e[pp + 12 - e_lo]]);
                }
                for (; pp < ne; pp += 4) h0 += ldAf(&rin[lds_e[pp - e_lo]]);
            } else {
                for (; pp < ne; pp += 4) h0 += ldAf(&rin[ldAi(&esrc[pp])]);
            }
            float hs = (h0 + h1) + (h2 + h3);
            hs += __shfl_xor(hs, 1, 64);
            hs += __shfl_xor(hs, 2, 64);
            if (sub == 0) {
                float res = hs + s_gam[l];
                if (l == DEPTH - 1) out[node] = res + b_out[0];
                else stAf(&((l & 1) ? rb0 : rb1)[node], res);
            }
        }
        if (l < DEPTH - 1) group_bar(g_arrive, gi, NB_G, gt++);
    }
}

// ---------------- launch ----------------

extern "C" void kernel_launch(void* const* d_in, const int* in_sizes, int n_in,
                              void* d_out, int out_size, void* d_ws, size_t ws_size,
                              hipStream_t stream) {
    const float* features = (const float*)d_in[0];  // [10000, 6]
    const float* W_in     = (const float*)d_in[1];  // [6, 512]
    const float* b_in     = (const float*)d_in[2];  // [512]
    const float* Ws       = (const float*)d_in[3];  // [10, 512, 512]
    const float* bs       = (const float*)d_in[4];  // [10, 512]
    const float* W_out    = (const float*)d_in[5];  // [512, 1]
    const float* b_out    = (const float*)d_in[6];  // [1]
    const int*   src      = (const int*)d_in[7];    // [160000]
    const int*   dst      = (const int*)d_in[8];    // [160000]
    float* out = (float*)d_out;                     // [10000]

    char* base = (char*)d_ws;
    // ---- zeroed region (flags/tags/deg/rb cleared every replay) ----
    int*   g_arrive = (int*)(base + 0);         // 40*128 -> 5120
    int*   rdv      = (int*)(base + 5120);      // 33*128 = 4224 -> pad 9472
    u64*   vslab    = (u64*)(base + 9472);      // 10*512*8 = 40960 -> 50432
    int*   deg      = (int*)(base + 50432);     // 40000  -> 90432 (pad 90496)
    float* rb0      = (float*)(base + 90496);   // 40064  -> 130560
    float* rb1      = (float*)(base + 130560);  // 40064  -> 170624
    const size_t MEMSET_END = 170624;
    // ---- non-zeroed (ordered by rdv flag / overwritten each launch) ----
    float* wbuf     = (float*)(base + 170624);  // 2048   -> 172672
    float* gamma_f  = (float*)(base + 172672);  // 64     -> 172736 (pad 172800)
    int*   esrc     = (int*)(base + 172800);    // 640000 -> 812800
    int*   row_ptr  = (int*)(base + 812800);    // 40004  -> 852804 (pad 852864)
    int*   cursor   = (int*)(base + 852864);    // 40000  -> 892864

    // clear flags/tags/deg/rb each replay (captured in graph)
    hipMemsetAsync(base, 0, MEMSET_END, stream);

    gcn_mega<<<NB, BT, 0, stream>>>(features, W_in, b_in, Ws, bs, W_out, b_out,
                                    src, dst, out,
                                    g_arrive, rdv, vslab, wbuf, gamma_f,
                                    deg, esrc, rb0, rb1, row_ptr, cursor);
}

// Round 14
// 185.123 us; speedup vs baseline: 1.0999x; 1.0999x over previous
//
#include <hip/hip_runtime.h>

// ============================================================================
// Algebraic collapse (layers 2..11 + head linear; A commutes with W):
//   out = A^10 x1 w~ + sum_l gamma_l A^(9-l) 1 + b_out
// Round-14: BYTE-FAITHFUL RESUBMISSION OF ROUND 4 (best measured: kernel
// 112.6us, dur_us 182.9, absmax 0) after two consecutive container failures
// on the throttled-chain experiment. Re-anchors the session to the proven
// optimum of this structure family:
//   graph group (40 blocks x 1024): deg -> scan -> CSR fill -> feature agg,
//     then waits on a one-shot rendezvous, then proj + 10 Horner steps.
//   chain group (33 blocks): 10 serial dense matvecs (1 row/wave) with private
//     33-block barriers; stores w~/gamma, flags rendezvous, and EXITS.
// Fence-free coherence (validated R3): all cross-block traffic via agent-scope
// relaxed atomics (sc1, coherent at Infinity Cache); per-wave vmcnt(0) drain
// before each flag store. No __threadfence anywhere.
// ============================================================================

#define N_NODES 10000
#define N_EDGES 160000
#define DEPTH   10

#define NB_G 40                  // graph blocks
#define NB_C 33                  // chain blocks (33*16 waves = 528 >= 513)
#define NB   (NB_G + NB_C)
#define BT   1024
#define NTHG (NB_G * BT)         // 40960 graph threads
#define NPB  250                 // nodes per graph block (40*250 = 10000)
#define ECAP 8192                // LDS edge-slice capacity (expected ~4000)

// ---- agent-scope (device-coherent, L2-bypassing) scalar accessors ----------
__device__ __forceinline__ float ldA(const float* p) {
    return __hip_atomic_load(p, __ATOMIC_RELAXED, __HIP_MEMORY_SCOPE_AGENT);
}
__device__ __forceinline__ int ldAi(const int* p) {
    return __hip_atomic_load(p, __ATOMIC_RELAXED, __HIP_MEMORY_SCOPE_AGENT);
}
__device__ __forceinline__ void stA(float* p, float v) {
    __hip_atomic_store(p, v, __ATOMIC_RELAXED, __HIP_MEMORY_SCOPE_AGENT);
}
__device__ __forceinline__ void stAi(int* p, int v) {
    __hip_atomic_store(p, v, __ATOMIC_RELAXED, __HIP_MEMORY_SCOPE_AGENT);
}

// ---- fence-free symmetric group barrier (n <= 1024 blocks) -----------------
__device__ __forceinline__ void group_bar(int* flags, int gi, int n, int target) {
    const int tx = threadIdx.x;
    asm volatile("s_waitcnt vmcnt(0)" ::: "memory");   // drain this wave's stores
    __syncthreads();                                   // all waves drained
    if (tx == 0) stAi(&flags[gi * 32], target);
    if (tx < n && tx != gi) {
        while (ldAi(&flags[tx * 32]) < target) __builtin_amdgcn_s_sleep(1);
    }
    __syncthreads();
}

extern "C" __global__ void __launch_bounds__(BT, 1) gcn_mega(
    const float* __restrict__ features, const float* __restrict__ W_in,
    const float* __restrict__ b_in, const float* __restrict__ Ws,
    const float* __restrict__ bs, const float* __restrict__ W_out,
    const float* __restrict__ b_out, const int* __restrict__ src,
    const int* __restrict__ dst, float* __restrict__ out,
    int* g_arrive, int* c_arrive, int* rdv, int* deg, int* row_ptr,
    int* cursor, int* esrc, float* vbufs, float* gamma,
    float* rb0, float* rb1)
{
    __shared__ int   lds_e[ECAP];     // 32 KB  edge slice
    __shared__ float s_Wb[4096];      // 16 KB  [512][8]: {W_in col (6), b, pad}
    __shared__ float s_vt[512];       //  2 KB  vtilde
    __shared__ float s_gam[16];
    __shared__ int   s_info[2];
    __shared__ int   s_wsum[16];

    const int tx = threadIdx.x;
    const int bx = blockIdx.x;

    // ======================= CHAIN GROUP (blocks >= NB_G) ===================
    if (bx >= NB_G) {
        const int gi   = bx - NB_G;                 // 0..32
        const int cw   = gi * (BT / 64) + (tx >> 6); // 0..527
        const int lane = tx & 63;
        for (int s = 0; s < DEPTH; s++) {
            const int l = 9 - s;
            if (cw <= 512) {
                float vin[8];
                if (s == 0) {
#pragma unroll
                    for (int c = 0; c < 8; c++) vin[c] = W_out[lane + 64 * c];
                } else {
                    const float* vb = vbufs + (s & 1) * 512;
#pragma unroll
                    for (int c = 0; c < 8; c++) vin[c] = ldA(vb + lane + 64 * c);
                }
                const float* rowp = (cw < 512)
                    ? (Ws + (size_t)l * (512 * 512) + (size_t)cw * 512)
                    : (bs + (size_t)l * 512);
                float acc = 0.f;
#pragma unroll
                for (int c = 0; c < 8; c++) acc += rowp[lane + 64 * c] * vin[c];
#pragma unroll
                for (int off = 32; off; off >>= 1) acc += __shfl_xor(acc, off, 64);
                if (lane == 0) {
                    if (cw < 512) stA(&vbufs[((s + 1) & 1) * 512 + cw], acc);
                    else          stA(&gamma[l], acc);
                }
            }
            if (s < DEPTH - 1) group_bar(c_arrive, gi, NB_C, s + 1);
        }
        // rendezvous: publish results and exit
        asm volatile("s_waitcnt vmcnt(0)" ::: "memory");
        __syncthreads();
        if (tx == 0) stAi(&rdv[gi * 32], 1);
        return;
    }

    // ======================= GRAPH GROUP (blocks < NB_G) ====================
    const int gi = bx;
    int gt = 1;

    // -------- P0: degree count + per-block W_in pack ------------------------
    {
        const int t0 = bx * BT + tx;
        for (int e = t0; e < N_EDGES; e += NTHG) atomicAdd(&deg[dst[e]], 1);
    }
    for (int idx = tx; idx < 4096; idx += BT) {
        int j = idx >> 3, k = idx & 7;
        float v = 0.f;
        if (k < 6) v = W_in[k * 512 + j];          // read-only: cached loads
        else if (k == 6) v = b_in[j];
        s_Wb[idx] = v;
    }
    group_bar(g_arrive, gi, NB_G, gt++);

    // -------- P1: prefix scan (graph block 0, shuffle-based) ----------------
    if (bx == 0) {
        const int lane = tx & 63, wid = tx >> 6;    // 16 waves
        const bool sact = tx < 1000;                // 1000 x 10 = 10000
        int lv[10];
        int ssum = 0;
        if (sact) {
#pragma unroll
            for (int i = 0; i < 10; i++) { lv[i] = ldAi(&deg[tx * 10 + i]); ssum += lv[i]; }
        }
        int v = ssum;                               // wave inclusive scan
#pragma unroll
        for (int off = 1; off < 64; off <<= 1) {
            int u = __shfl_up(v, off, 64);
            if (lane >= off) v += u;
        }
        if (lane == 63) s_wsum[wid] = v;
        __syncthreads();
        if (wid == 0) {                             // scan the 16 wave totals
            int w = (lane < 16) ? s_wsum[lane] : 0;
#pragma unroll
            for (int off = 1; off < 16; off <<= 1) {
                int u = __shfl_up(w, off, 64);
                if (lane >= off) w += u;
            }
            if (lane < 16) s_wsum[lane] = w;
        }
        __syncthreads();
        if (sact) {
            int run = (wid ? s_wsum[wid - 1] : 0) + (v - ssum);  // exclusive
#pragma unroll
            for (int i = 0; i < 10; i++) {
                stAi(&row_ptr[tx * 10 + i], run);
                stAi(&cursor[tx * 10 + i], run);
                run += lv[i];
            }
            if (tx == 999) stAi(&row_ptr[N_NODES], run);
        }
    }
    group_bar(g_arrive, gi, NB_G, gt++);

    // -------- P2: CSR fill --------------------------------------------------
    {
        const int t0 = bx * BT + tx;
        for (int e = t0; e < N_EDGES; e += NTHG) {
            int d = dst[e];
            int sv = src[e];
            int pos = atomicAdd(&cursor[d], 1);
            stAi(&esrc[pos], sv);
        }
    }
    group_bar(g_arrive, gi, NB_G, gt++);

    // -------- P3: stage edge slice -> LDS; aggregate features ---------------
    if (tx == 0) {
        s_info[0] = ldAi(&row_ptr[bx * NPB]);
        s_info[1] = ldAi(&row_ptr[bx * NPB + NPB]);
    }
    __syncthreads();
    const int e_lo = s_info[0];
    const int slen = s_info[1] - e_lo;
    const bool use_lds = (slen <= ECAP);
    if (use_lds) {
        for (int i = tx; i < slen; i += BT) lds_e[i] = ldAi(&esrc[e_lo + i]);
    }
    __syncthreads();

    const int node = bx * NPB + (tx >> 2);          // 4 threads/node
    const int sub  = tx & 3;
    const bool act = tx < 4 * NPB;                  // 1000 active threads
    int ns = 0, ne = 0;
    float a0 = 0.f, a1 = 0.f, a2 = 0.f, a3 = 0.f, a4 = 0.f, a5 = 0.f;
    if (act) {
        ns = ldAi(&row_ptr[node]);
        ne = ldAi(&row_ptr[node + 1]);
        if (use_lds) {
            for (int pp = ns + sub; pp < ne; pp += 4) {
                int j = lds_e[pp - e_lo];
                const float2* f = (const float2*)(features + (size_t)j * 6);
                float2 f0 = f[0], f1 = f[1], f2 = f[2];
                a0 += f0.x; a1 += f0.y; a2 += f1.x;
                a3 += f1.y; a4 += f2.x; a5 += f2.y;
            }
        } else {
            for (int pp = ns + sub; pp < ne; pp += 4) {
                int j = ldAi(&esrc[pp]);
                const float2* f = (const float2*)(features + (size_t)j * 6);
                float2 f0 = f[0], f1 = f[1], f2 = f[2];
                a0 += f0.x; a1 += f0.y; a2 += f1.x;
                a3 += f1.y; a4 += f2.x; a5 += f2.y;
            }
        }
        a0 += __shfl_xor(a0, 1, 64); a0 += __shfl_xor(a0, 2, 64);
        a1 += __shfl_xor(a1, 1, 64); a1 += __shfl_xor(a1, 2, 64);
        a2 += __shfl_xor(a2, 1, 64); a2 += __shfl_xor(a2, 2, 64);
        a3 += __shfl_xor(a3, 1, 64); a3 += __shfl_xor(a3, 2, 64);
        a4 += __shfl_xor(a4, 1, 64); a4 += __shfl_xor(a4, 2, 64);
        a5 += __shfl_xor(a5, 1, 64); a5 += __shfl_xor(a5, 2, 64);
    }

    // -------- rendezvous: wait for chain group (one-shot, read-only) --------
    if (tx < NB_C) {
        while (ldAi(&rdv[tx * 32]) < 1) __builtin_amdgcn_s_sleep(1);
    }
    __syncthreads();
    if (tx < 512) s_vt[tx] = ldA(&vbufs[tx]);       // w~ (chain final output)
    if (tx >= 512 && tx < 512 + DEPTH) s_gam[tx - 512] = ldA(&gamma[tx - 512]);
    __syncthreads();

    // -------- P10: z = relu(a . W_in + b_in) . w~  -> rb0 -------------------
    if (act) {
        const float4* Wb4 = (const float4*)s_Wb;
        float zacc = 0.f;
#pragma unroll 4
        for (int jj = 0; jj < 128; jj++) {
            int j = (jj << 2) | sub;                // 4-way split of j-range
            float4 wA = Wb4[2 * j];                 // w0..w3
            float4 wB = Wb4[2 * j + 1];             // w4, w5, b, pad
            float tv = wB.z + a0 * wA.x + a1 * wA.y + a2 * wA.z +
                       a3 * wA.w + a4 * wB.x + a5 * wB.y;
            zacc += fmaxf(tv, 0.f) * s_vt[j];
        }
        zacc += __shfl_xor(zacc, 1, 64);
        zacc += __shfl_xor(zacc, 2, 64);
        if (sub == 0) stA(&rb0[node], zacc);
    }
    group_bar(g_arrive, gi, NB_G, gt++);

    // -------- P11..P20: Horner  r <- A r + gamma[l] -------------------------
    for (int l = 0; l < DEPTH; l++) {
        if (act) {
            const float* rin = (l & 1) ? rb1 : rb0;
            float h0 = 0.f, h1 = 0.f;
            int pp = ns + sub;
            if (use_lds) {
                for (; pp + 4 < ne; pp += 8) {
                    h0 += ldA(&rin[lds_e[pp - e_lo]]);
                    h1 += ldA(&rin[lds_e[pp + 4 - e_lo]]);
                }
                if (pp < ne) h0 += ldA(&rin[lds_e[pp - e_lo]]);
            } else {
                for (; pp + 4 < ne; pp += 8) {
                    h0 += ldA(&rin[ldAi(&esrc[pp])]);
                    h1 += ldA(&rin[ldAi(&esrc[pp + 4])]);
                }
                if (pp < ne) h0 += ldA(&rin[ldAi(&esrc[pp])]);
            }
            float hs = h0 + h1;
            hs += __shfl_xor(hs, 1, 64);
            hs += __shfl_xor(hs, 2, 64);
            if (sub == 0) {
                float res = hs + s_gam[l];
                if (l == DEPTH - 1) out[node] = res + b_out[0];
                else stA(&((l & 1) ? rb0 : rb1)[node], res);
            }
        }
        if (l < DEPTH - 1) group_bar(g_arrive, gi, NB_G, gt++);
    }
}

// ---------------- launch ----------------

extern "C" void kernel_launch(void* const* d_in, const int* in_sizes, int n_in,
                              void* d_out, int out_size, void* d_ws, size_t ws_size,
                              hipStream_t stream) {
    const float* features = (const float*)d_in[0];  // [10000, 6]
    const float* W_in     = (const float*)d_in[1];  // [6, 512]
    const float* b_in     = (const float*)d_in[2];  // [512]
    const float* Ws       = (const float*)d_in[3];  // [10, 512, 512]
    const float* bs       = (const float*)d_in[4];  // [10, 512]
    const float* W_out    = (const float*)d_in[5];  // [512, 1]
    const float* b_out    = (const float*)d_in[6];  // [1]
    const int*   src      = (const int*)d_in[7];    // [160000]
    const int*   dst      = (const int*)d_in[8];    // [160000]
    float* out = (float*)d_out;                     // [10000]

    char* base = (char*)d_ws;
    int*   g_arrive = (int*)(base + 0);        // 40*128 B
    int*   c_arrive = (int*)(base + 5120);     // 40*128 B (33 used)
    int*   rdv      = (int*)(base + 10240);    // 40*128 B (33 used)
    int*   deg      = (int*)(base + 15360);    // 40000 B  (memset 0..55360)
    int*   row_ptr  = (int*)(base + 55424);    // 40004 B
    int*   cursor   = (int*)(base + 95488);    // 40000 B
    int*   esrc     = (int*)(base + 135552);   // 640000 B
    float* vbufs    = (float*)(base + 775552); // 4096 B (2 x 512)
    float* gamma    = (float*)(base + 779648); // 64 B
    float* rb0      = (float*)(base + 779712); // 40000 B
    float* rb1      = (float*)(base + 819712); // 40000 B

    // zero barrier/rendezvous flags + deg (captured in graph => every replay)
    hipMemsetAsync(base, 0, 55360, stream);

    gcn_mega<<<NB, BT, 0, stream>>>(features, W_in, b_in, Ws, bs, W_out, b_out,
                                    src, dst, out,
                                    g_arrive, c_arrive, rdv, deg, row_ptr,
                                    cursor, esrc, vbufs, gamma, rb0, rb1);
}